// Round 2
// baseline (1193.171 us; speedup 1.0000x reference)
//
#include <hip/hip_runtime.h>

#define NNODES 50000
#define NREL   8
#define HID    64
#define NCLS   16
#define NEDGE  1600000
#define NTGT   8192
#define NBINS  (NNODES * NREL)

__device__ __forceinline__ float elu1(float x) { return x > 0.f ? x : expm1f(x); }

// --- K1: per-(dst,rel) counts; also records each edge's slot within its bin --
__global__ void count_kernel(const int* __restrict__ ei, const int* __restrict__ et,
                             int* __restrict__ cnt, int* __restrict__ epos) {
  int e = blockIdx.x * blockDim.x + threadIdx.x;
  if (e >= NEDGE) return;
  int dst = ei[NEDGE + e];
  int rel = et[e];
  epos[e] = atomicAdd(&cnt[dst * NREL + rel], 1);
}

// --- K2: single-block exclusive scan over 400K bins, int4-coalesced ----------
__global__ void scan_kernel(const int* __restrict__ cnt, int* __restrict__ binptr) {
  __shared__ int s_w[16];
  __shared__ int s_carry, s_tot;
  int tid = threadIdx.x, lane = tid & 63, wid = tid >> 6;
  if (tid == 0) s_carry = 0;
  __syncthreads();
  for (int base = 0; base < NBINS; base += 4096) {
    int i = base + tid * 4;
    int4 c = make_int4(0, 0, 0, 0);
    if (i < NBINS) c = *(const int4*)(cnt + i);
    int p0 = c.x, p1 = c.x + c.y, p2 = p1 + c.z, sum = p2 + c.w;
    int v = sum;
#pragma unroll
    for (int off = 1; off < 64; off <<= 1) {
      int u = __shfl_up(v, off);
      if (lane >= off) v += u;
    }
    if (lane == 63) s_w[wid] = v;
    __syncthreads();
    if (tid == 0) {
      int run = 0;
#pragma unroll
      for (int j = 0; j < 16; ++j) { int t = s_w[j]; s_w[j] = run; run += t; }
      s_tot = run;
    }
    __syncthreads();
    int excl = s_carry + s_w[wid] + (v - sum);
    if (i < NBINS) {
      int4 o = make_int4(excl, excl + p0, excl + p1, excl + p2);
      *(int4*)(binptr + i) = o;
    }
    __syncthreads();
    if (tid == 0) s_carry += s_tot;
    __syncthreads();
  }
  if (threadIdx.x == 0) binptr[NBINS] = s_carry;  // == NEDGE
}

// --- K3: atomic-free scatter into bin-sorted CSR -----------------------------
__global__ void scatter_kernel(const int* __restrict__ ei, const int* __restrict__ et,
                               const int* __restrict__ epos, const int* __restrict__ binptr,
                               int* __restrict__ ep) {
  int e = blockIdx.x * blockDim.x + threadIdx.x;
  if (e >= NEDGE) return;
  int src = ei[e];
  int dst = ei[NEDGE + e];
  int rel = et[e];
  int bin = dst * NREL + rel;
  ep[binptr[bin] + epos[e]] = src;
}

// --- K4: conv1 — one wave per node, lane = channel; per-rel segments ---------
__global__ __launch_bounds__(256, 8) void conv1_kernel(
    const int* __restrict__ binptr, const int* __restrict__ ep,
    const float* __restrict__ w1, const float* __restrict__ root1,
    const float* __restrict__ bias1, float* __restrict__ h1) {
  int wave = blockIdx.x * (blockDim.x >> 6) + (threadIdx.x >> 6);
  if (wave >= NNODES) return;
  int lane = threadIdx.x & 63;
  int n = wave;
  const float* wl = w1 + lane;
  int b = binptr[n * NREL];
  float acc = 0.f;
#pragma unroll
  for (int r = 0; r < NREL; ++r) {
    int eend = binptr[n * NREL + r + 1];
    const float* wr = wl + (size_t)r * (NNODES * HID);
    float s = 0.f;
    int e = b;
    for (; e + 4 <= eend; e += 4) {
      int s0 = ep[e], s1 = ep[e + 1], s2 = ep[e + 2], s3 = ep[e + 3];
      float a0 = wr[s0 << 6], a1 = wr[s1 << 6], a2 = wr[s2 << 6], a3 = wr[s3 << 6];
      s += a0; s += a1; s += a2; s += a3;
    }
    for (; e < eend; ++e) s += wr[ep[e] << 6];
    int c = eend - b;
    if (c) acc += s / (float)c;   // per-relation MEAN, summed over relations
    b = eend;
  }
  float v = acc + root1[(n << 6) + lane] + bias1[lane];
  h1[(n << 6) + lane] = elu1(v);
}

// --- K5: conv2 — 2 nodes per wave (halves w2 re-reads); only dst < NTGT ------
__global__ __launch_bounds__(256, 4) void conv2_kernel(
    const int* __restrict__ binptr, const int* __restrict__ ep,
    const float* __restrict__ h1, const float* __restrict__ w2,
    const float* __restrict__ root2, const float* __restrict__ bias2,
    float* __restrict__ h2) {
  int wave = blockIdx.x * (blockDim.x >> 6) + (threadIdx.x >> 6);
  if (wave >= NTGT / 2) return;
  int lane = threadIdx.x & 63;
  int n0 = wave * 2, n1 = n0 + 1;
  const float* hl = h1 + lane;
  float acc0[NREL], acc1[NREL];

  int b = binptr[n0 * NREL];
#pragma unroll
  for (int r = 0; r < NREL; ++r) {
    int eend = binptr[n0 * NREL + r + 1];
    float s = 0.f;
    int e = b;
    for (; e + 2 <= eend; e += 2) { float a = hl[ep[e] << 6], bb = hl[ep[e + 1] << 6]; s += a; s += bb; }
    for (; e < eend; ++e) s += hl[ep[e] << 6];
    int c = eend - b;
    acc0[r] = c ? s / (float)c : 0.f;
    b = eend;
  }
  b = binptr[n1 * NREL];
#pragma unroll
  for (int r = 0; r < NREL; ++r) {
    int eend = binptr[n1 * NREL + r + 1];
    float s = 0.f;
    int e = b;
    for (; e + 2 <= eend; e += 2) { float a = hl[ep[e] << 6], bb = hl[ep[e + 1] << 6]; s += a; s += bb; }
    for (; e < eend; ++e) s += hl[ep[e] << 6];
    int c = eend - b;
    acc1[r] = c ? s / (float)c : 0.f;
    b = eend;
  }

  float hv0 = hl[n0 << 6], hv1 = hl[n1 << 6];
  float bz = bias2[lane];
  float o0 = bz, o1 = bz;
#pragma unroll
  for (int r = 0; r < NREL; ++r) {
    const float* w2r = w2 + (r << 12) + lane;
#pragma unroll
    for (int k = 0; k < HID; ++k) {
      float w = w2r[k << 6];
      o0 = fmaf(__shfl(acc0[r], k), w, o0);
      o1 = fmaf(__shfl(acc1[r], k), w, o1);
    }
  }
#pragma unroll
  for (int k = 0; k < HID; ++k) {
    float w = root2[(k << 6) + lane];
    o0 = fmaf(__shfl(hv0, k), w, o0);
    o1 = fmaf(__shfl(hv1, k), w, o1);
  }
  h2[(n0 << 6) + lane] = elu1(o0);
  h2[(n1 << 6) + lane] = elu1(o1);
}

// --- K6: linear head ---------------------------------------------------------
__global__ void head_kernel(const float* __restrict__ h2, const float* __restrict__ lin_w,
                            const float* __restrict__ lin_b, float* __restrict__ out) {
  int t = blockIdx.x * blockDim.x + threadIdx.x;
  if (t >= NTGT * NCLS) return;
  int n = t >> 4, c = t & 15;
  float acc = lin_b[c];
#pragma unroll
  for (int k = 0; k < HID; ++k)
    acc = fmaf(h2[(n << 6) + k], lin_w[k * NCLS + c], acc);
  out[t] = acc;
}

extern "C" void kernel_launch(void* const* d_in, const int* in_sizes, int n_in,
                              void* d_out, int out_size, void* d_ws, size_t ws_size,
                              hipStream_t stream) {
  const int*   ei    = (const int*)d_in[0];
  const int*   et    = (const int*)d_in[1];
  const float* w1    = (const float*)d_in[3];
  const float* root1 = (const float*)d_in[4];
  const float* bias1 = (const float*)d_in[5];
  const float* w2    = (const float*)d_in[6];
  const float* root2 = (const float*)d_in[7];
  const float* bias2 = (const float*)d_in[8];
  const float* lin_w = (const float*)d_in[9];
  const float* lin_b = (const float*)d_in[10];
  float* out = (float*)d_out;

  // Workspace layout (~22.9 MB). Region A [0, 12.8MB) is time-shared:
  //   cnt (1.6MB) + epos (6.4MB) live until scatter; h1 (12.8MB) written by conv1 after.
  char* ws = (char*)d_ws;
  float* h1     = (float*)ws;
  int*   cnt    = (int*)ws;
  int*   epos   = (int*)(ws + (size_t)NBINS * 4);
  char*  p      = ws + (size_t)NNODES * HID * 4;
  int*   binptr = (int*)p;
  p += ((size_t)(NBINS + 1) * 4 + 255) & ~(size_t)255;
  int*   ep     = (int*)p;
  p += (size_t)NEDGE * 4;
  float* h2     = (float*)p;

  hipMemsetAsync(cnt, 0, (size_t)NBINS * sizeof(int), stream);
  count_kernel<<<(NEDGE + 255) / 256, 256, 0, stream>>>(ei, et, cnt, epos);
  scan_kernel<<<1, 1024, 0, stream>>>(cnt, binptr);
  scatter_kernel<<<(NEDGE + 255) / 256, 256, 0, stream>>>(ei, et, epos, binptr, ep);
  conv1_kernel<<<(NNODES + 3) / 4, 256, 0, stream>>>(binptr, ep, w1, root1, bias1, h1);
  conv2_kernel<<<(NTGT / 2 + 3) / 4, 256, 0, stream>>>(binptr, ep, h1, w2, root2, bias2, h2);
  head_kernel<<<(NTGT * NCLS + 255) / 256, 256, 0, stream>>>(h2, lin_w, lin_b, out);
}

// Round 3
// 556.399 us; speedup vs baseline: 2.1445x; 2.1445x over previous
//
#include <hip/hip_runtime.h>

#define NNODES 50000
#define NREL   8
#define HID    64
#define NCLS   16
#define NEDGE  1600000
#define NTGT   8192
#define NBINS  (NNODES * NREL)
#define CHUNK  1024
#define NCHUNK ((NBINS + CHUNK - 1) / CHUNK)   // 391

__device__ __forceinline__ float elu1(float x) { return x > 0.f ? x : expm1f(x); }

// select inv[r] (compile-time-indexed array) by runtime r via cndmask tree
__device__ __forceinline__ float sel8(const float inv[8], int r) {
  float lo = (r & 2) ? ((r & 1) ? inv[3] : inv[2]) : ((r & 1) ? inv[1] : inv[0]);
  float hi = (r & 2) ? ((r & 1) ? inv[7] : inv[6]) : ((r & 1) ? inv[5] : inv[4]);
  return (r & 4) ? hi : lo;
}

// --- K1: per-(dst,rel) counts; epos[e] = slot within bin ---------------------
__global__ void count_kernel(const int* __restrict__ ei, const int* __restrict__ et,
                             int* __restrict__ cnt, int* __restrict__ epos) {
  int e = blockIdx.x * blockDim.x + threadIdx.x;
  if (e >= NEDGE) return;
  int dst = ei[NEDGE + e];
  int rel = et[e];
  epos[e] = atomicAdd(&cnt[dst * NREL + rel], 1);
}

// --- K2a: per-chunk sums -----------------------------------------------------
__global__ void chunk_sum_kernel(const int* __restrict__ cnt, int* __restrict__ csum) {
  __shared__ int sw[4];
  int t = threadIdx.x, lane = t & 63, wid = t >> 6;
  int i = blockIdx.x * CHUNK + t * 4;
  int s = 0;
  if (i < NBINS) { int4 c = *(const int4*)(cnt + i); s = c.x + c.y + c.z + c.w; }
#pragma unroll
  for (int off = 32; off >= 1; off >>= 1) s += __shfl_xor(s, off);
  if (lane == 0) sw[wid] = s;
  __syncthreads();
  if (t == 0) csum[blockIdx.x] = sw[0] + sw[1] + sw[2] + sw[3];
}

// --- K2b: scan the 391 chunk sums (1 block) ---------------------------------
__global__ void scan_csum_kernel(const int* __restrict__ csum, int* __restrict__ cbase) {
  __shared__ int sw[8];
  int t = threadIdx.x, lane = t & 63, wid = t >> 6;  // 512 threads
  int v0 = (t < NCHUNK) ? csum[t] : 0;
  int v = v0;
#pragma unroll
  for (int off = 1; off < 64; off <<= 1) {
    int u = __shfl_up(v, off);
    if (lane >= off) v += u;
  }
  if (lane == 63) sw[wid] = v;
  __syncthreads();
  if (t == 0) {
    int run = 0;
#pragma unroll
    for (int j = 0; j < 8; ++j) { int x = sw[j]; sw[j] = run; run += x; }
  }
  __syncthreads();
  if (t < NCHUNK) cbase[t] = sw[wid] + (v - v0);
}

// --- K2c: per-chunk exclusive scan + chunk base -> binptr --------------------
__global__ void scan_write_kernel(const int* __restrict__ cnt, const int* __restrict__ cbase,
                                  int* __restrict__ binptr) {
  __shared__ int sw[4];
  int t = threadIdx.x, lane = t & 63, wid = t >> 6;
  int i = blockIdx.x * CHUNK + t * 4;
  int4 c = make_int4(0, 0, 0, 0);
  if (i < NBINS) c = *(const int4*)(cnt + i);
  int p0 = c.x, p1 = p0 + c.y, p2 = p1 + c.z, s = p2 + c.w;
  int v = s;
#pragma unroll
  for (int off = 1; off < 64; off <<= 1) {
    int u = __shfl_up(v, off);
    if (lane >= off) v += u;
  }
  if (lane == 63) sw[wid] = v;
  __syncthreads();
  if (t == 0) {
    int run = 0;
#pragma unroll
    for (int j = 0; j < 4; ++j) { int x = sw[j]; sw[j] = run; run += x; }
  }
  __syncthreads();
  if (i < NBINS) {
    int excl = cbase[blockIdx.x] + sw[wid] + (v - s);
    *(int4*)(binptr + i) = make_int4(excl, excl + p0, excl + p1, excl + p2);
  }
  if (blockIdx.x == 0 && t == 0) binptr[NBINS] = NEDGE;
}

// --- K3: atomic-free scatter; pack src | rel<<16 (src < 65536) ---------------
__global__ void scatter_kernel(const int* __restrict__ ei, const int* __restrict__ et,
                               const int* __restrict__ epos, const int* __restrict__ binptr,
                               int* __restrict__ ep) {
  int e = blockIdx.x * blockDim.x + threadIdx.x;
  if (e >= NEDGE) return;
  int src = ei[e];
  int dst = ei[NEDGE + e];
  int rel = et[e];
  int bin = dst * NREL + rel;
  ep[binptr[bin] + epos[e]] = src | (rel << 16);
}

// --- K4: conv1 — one wave per node, whole-range loop, 8 gathers in flight ----
__global__ void conv1_kernel(const int* __restrict__ binptr, const int* __restrict__ ep,
                             const float* __restrict__ w1, const float* __restrict__ root1,
                             const float* __restrict__ bias1, float* __restrict__ h1) {
  int wave = blockIdx.x * (blockDim.x >> 6) + (threadIdx.x >> 6);
  if (wave >= NNODES) return;
  int lane = threadIdx.x & 63;
  int n = wave;
  const float* wl = w1 + lane;
  int bp[9];
#pragma unroll
  for (int r = 0; r <= NREL; ++r) bp[r] = binptr[n * NREL + r];
  float inv[8];
#pragma unroll
  for (int r = 0; r < NREL; ++r) inv[r] = 1.0f / (float)max(bp[r + 1] - bp[r], 1);
  int b0 = bp[0], b8 = bp[8];
  float acc = 0.f;
  int e = b0;
  for (; e + 8 <= b8; e += 8) {
    int p0 = ep[e],     p1 = ep[e + 1], p2 = ep[e + 2], p3 = ep[e + 3];
    int p4 = ep[e + 4], p5 = ep[e + 5], p6 = ep[e + 6], p7 = ep[e + 7];
    float a0 = wl[((p0 >> 16) * NNODES + (p0 & 0xFFFF)) << 6];
    float a1 = wl[((p1 >> 16) * NNODES + (p1 & 0xFFFF)) << 6];
    float a2 = wl[((p2 >> 16) * NNODES + (p2 & 0xFFFF)) << 6];
    float a3 = wl[((p3 >> 16) * NNODES + (p3 & 0xFFFF)) << 6];
    float a4 = wl[((p4 >> 16) * NNODES + (p4 & 0xFFFF)) << 6];
    float a5 = wl[((p5 >> 16) * NNODES + (p5 & 0xFFFF)) << 6];
    float a6 = wl[((p6 >> 16) * NNODES + (p6 & 0xFFFF)) << 6];
    float a7 = wl[((p7 >> 16) * NNODES + (p7 & 0xFFFF)) << 6];
    acc = fmaf(a0, sel8(inv, p0 >> 16), acc);
    acc = fmaf(a1, sel8(inv, p1 >> 16), acc);
    acc = fmaf(a2, sel8(inv, p2 >> 16), acc);
    acc = fmaf(a3, sel8(inv, p3 >> 16), acc);
    acc = fmaf(a4, sel8(inv, p4 >> 16), acc);
    acc = fmaf(a5, sel8(inv, p5 >> 16), acc);
    acc = fmaf(a6, sel8(inv, p6 >> 16), acc);
    acc = fmaf(a7, sel8(inv, p7 >> 16), acc);
  }
  for (; e + 4 <= b8; e += 4) {
    int p0 = ep[e], p1 = ep[e + 1], p2 = ep[e + 2], p3 = ep[e + 3];
    float a0 = wl[((p0 >> 16) * NNODES + (p0 & 0xFFFF)) << 6];
    float a1 = wl[((p1 >> 16) * NNODES + (p1 & 0xFFFF)) << 6];
    float a2 = wl[((p2 >> 16) * NNODES + (p2 & 0xFFFF)) << 6];
    float a3 = wl[((p3 >> 16) * NNODES + (p3 & 0xFFFF)) << 6];
    acc = fmaf(a0, sel8(inv, p0 >> 16), acc);
    acc = fmaf(a1, sel8(inv, p1 >> 16), acc);
    acc = fmaf(a2, sel8(inv, p2 >> 16), acc);
    acc = fmaf(a3, sel8(inv, p3 >> 16), acc);
  }
  for (; e < b8; ++e) {
    int p = ep[e];
    float a = wl[((p >> 16) * NNODES + (p & 0xFFFF)) << 6];
    acc = fmaf(a, sel8(inv, p >> 16), acc);
  }
  float v = acc + root1[(n << 6) + lane] + bias1[lane];
  h1[(n << 6) + lane] = elu1(v);
}

// --- K5: conv2 — per-relation LDS-staged w2; 4 waves × 8 nodes per block -----
__global__ __launch_bounds__(256) void conv2_kernel(
    const int* __restrict__ binptr, const int* __restrict__ ep,
    const float* __restrict__ h1, const float* __restrict__ w2,
    const float* __restrict__ root2, const float* __restrict__ bias2,
    float* __restrict__ h2) {
  __shared__ float sW[HID * HID];  // 16 KB: current relation's weight
  int t = threadIdx.x, lane = t & 63, wid = t >> 6;
  int nodeBase = blockIdx.x * 32 + wid * 8;  // 32 nodes per block
  const float* hl = h1 + lane;
  float o[8];
#pragma unroll
  for (int i = 0; i < 8; ++i) o[i] = 0.f;

  for (int r = 0; r < NREL; ++r) {
    if (r) __syncthreads();
#pragma unroll
    for (int i = 0; i < 16; ++i)
      sW[t + i * 256] = w2[(r << 12) + t + i * 256];
    __syncthreads();
    float acc[8];
#pragma unroll
    for (int i = 0; i < 8; ++i) {
      int n = nodeBase + i;
      int bb = binptr[n * NREL + r], ee = binptr[n * NREL + r + 1];
      float s = 0.f;
      int e = bb;
      for (; e + 2 <= ee; e += 2) {
        float a0 = hl[(ep[e] & 0xFFFF) << 6];
        float a1 = hl[(ep[e + 1] & 0xFFFF) << 6];
        s += a0; s += a1;
      }
      for (; e < ee; ++e) s += hl[(ep[e] & 0xFFFF) << 6];
      int c = ee - bb;
      acc[i] = c ? s * (1.0f / (float)c) : 0.f;
    }
#pragma unroll
    for (int k = 0; k < HID; ++k) {
      float w = sW[(k << 6) + lane];
#pragma unroll
      for (int i = 0; i < 8; ++i) o[i] = fmaf(__shfl(acc[i], k), w, o[i]);
    }
  }

  // root (self) term
  __syncthreads();
#pragma unroll
  for (int i = 0; i < 16; ++i) sW[t + i * 256] = root2[t + i * 256];
  __syncthreads();
  float hv[8];
#pragma unroll
  for (int i = 0; i < 8; ++i) hv[i] = hl[(nodeBase + i) << 6];
#pragma unroll
  for (int k = 0; k < HID; ++k) {
    float w = sW[(k << 6) + lane];
#pragma unroll
    for (int i = 0; i < 8; ++i) o[i] = fmaf(__shfl(hv[i], k), w, o[i]);
  }
  float bz = bias2[lane];
#pragma unroll
  for (int i = 0; i < 8; ++i)
    h2[((nodeBase + i) << 6) + lane] = elu1(o[i] + bz);
}

// --- K6: linear head ---------------------------------------------------------
__global__ void head_kernel(const float* __restrict__ h2, const float* __restrict__ lin_w,
                            const float* __restrict__ lin_b, float* __restrict__ out) {
  int t = blockIdx.x * blockDim.x + threadIdx.x;
  if (t >= NTGT * NCLS) return;
  int n = t >> 4, c = t & 15;
  float acc = lin_b[c];
#pragma unroll
  for (int k = 0; k < HID; ++k)
    acc = fmaf(h2[(n << 6) + k], lin_w[k * NCLS + c], acc);
  out[t] = acc;
}

extern "C" void kernel_launch(void* const* d_in, const int* in_sizes, int n_in,
                              void* d_out, int out_size, void* d_ws, size_t ws_size,
                              hipStream_t stream) {
  const int*   ei    = (const int*)d_in[0];
  const int*   et    = (const int*)d_in[1];
  const float* w1    = (const float*)d_in[3];
  const float* root1 = (const float*)d_in[4];
  const float* bias1 = (const float*)d_in[5];
  const float* w2    = (const float*)d_in[6];
  const float* root2 = (const float*)d_in[7];
  const float* bias2 = (const float*)d_in[8];
  const float* lin_w = (const float*)d_in[9];
  const float* lin_b = (const float*)d_in[10];
  float* out = (float*)d_out;

  // Workspace (~23 MB). [0, 12.8MB) time-shared: cnt(1.6)+epos(6.4) die before
  // conv1 writes h1(12.8) there.
  char* ws = (char*)d_ws;
  float* h1     = (float*)ws;
  int*   cnt    = (int*)ws;
  int*   epos   = (int*)(ws + (size_t)NBINS * 4);
  char*  p      = ws + (size_t)NNODES * HID * 4;
  int*   binptr = (int*)p;  p += ((size_t)(NBINS + 1) * 4 + 255) & ~(size_t)255;
  int*   ep     = (int*)p;  p += (size_t)NEDGE * 4;
  float* h2     = (float*)p; p += (size_t)NTGT * HID * 4;
  int*   csum   = (int*)p;  p += ((size_t)NCHUNK * 4 + 255) & ~(size_t)255;
  int*   cbase  = (int*)p;

  hipMemsetAsync(cnt, 0, (size_t)NBINS * sizeof(int), stream);
  count_kernel<<<(NEDGE + 255) / 256, 256, 0, stream>>>(ei, et, cnt, epos);
  chunk_sum_kernel<<<NCHUNK, 256, 0, stream>>>(cnt, csum);
  scan_csum_kernel<<<1, 512, 0, stream>>>(csum, cbase);
  scan_write_kernel<<<NCHUNK, 256, 0, stream>>>(cnt, cbase, binptr);
  scatter_kernel<<<(NEDGE + 255) / 256, 256, 0, stream>>>(ei, et, epos, binptr, ep);
  conv1_kernel<<<(NNODES + 3) / 4, 256, 0, stream>>>(binptr, ep, w1, root1, bias1, h1);
  conv2_kernel<<<NTGT / 32, 256, 0, stream>>>(binptr, ep, h1, w2, root2, bias2, h2);
  head_kernel<<<(NTGT * NCLS + 255) / 256, 256, 0, stream>>>(h2, lin_w, lin_b, out);
}